// Round 1
// baseline (880.666 us; speedup 1.0000x reference)
//
#include <hip/hip_runtime.h>
#include <cstddef>

#define NB 32       // batch
#define NN 2000     // nodes
#define NRD 32      // raw feature dim
#define NE 128      // embed dim
#define NH 256      // hidden dim
#define NA 8        // agents
#define ACTION_NORM 2000.0f

// ---------------------------------------------------------------- init
__global__ void k_init(unsigned* dmax_u, float* actions,
                       const int* __restrict__ fixed_actions,
                       const int* __restrict__ fixed_ids) {
    int t = threadIdx.x;
    if (t == 0) *dmax_u = 0u;
    if (t < NB * NA) {
        int b = t / NA, a = t % NA;
        float v = -1.0f;
        for (int j = 0; j < 3; ++j)
            if (fixed_ids[j] == a) v = (float)fixed_actions[j * NB + b] / ACTION_NORM;
        actions[t] = v;
    }
}

// ---------------------------------------------------------------- global max of dm
__global__ __launch_bounds__(256) void k_max(const float* __restrict__ dm,
                                             unsigned* dmax_u, int n) {
    __shared__ float sh[256];
    float m = 0.0f;
    for (int i = blockIdx.x * blockDim.x + threadIdx.x; i < n; i += gridDim.x * blockDim.x)
        m = fmaxf(m, dm[i]);
    sh[threadIdx.x] = m; __syncthreads();
    for (int s = 128; s > 0; s >>= 1) {
        if (threadIdx.x < s) sh[threadIdx.x] = fmaxf(sh[threadIdx.x], sh[threadIdx.x + s]);
        __syncthreads();
    }
    if (threadIdx.x == 0) atomicMax(dmax_u, __float_as_uint(sh[0]));
}

// ---------------------------------------------------------------- sim rows (unnormalized) + inv rowsum
__global__ __launch_bounds__(256) void k_sim(const float* __restrict__ dm,
                                             const unsigned* __restrict__ dmax_u,
                                             float* __restrict__ sim,
                                             float* __restrict__ inv_rs) {
    __shared__ float sh[256];
    const int n = blockIdx.x;
    const float inv = 1.0f / __uint_as_float(*dmax_u);
    float s = 0.0f;
    for (int m = threadIdx.x; m < NN; m += 256) {
        float e = expf(-dm[(size_t)n * NN + m] * inv);
        sim[(size_t)n * NN + m] = e;
        s += e;
    }
    sh[threadIdx.x] = s; __syncthreads();
    for (int st = 128; st > 0; st >>= 1) {
        if (threadIdx.x < st) sh[threadIdx.x] += sh[threadIdx.x + st];
        __syncthreads();
    }
    if (threadIdx.x == 0) inv_rs[n] = 1.0f / sh[0];
}

// ---------------------------------------------------------------- generic fp32 SGEMM 128x128, 8x8/thread
// C[M,N] = op(A[M,K] @ B[K,N]); optional rowScale (per row), bias (per col), relu,
// optional permuted store: out = (r%permD)*permStride + (r/permD)*N + c
__global__ __launch_bounds__(256) void sgemm_k(
        const float* __restrict__ A, const float* __restrict__ B,
        float* __restrict__ C, int M, int N, int K,
        const float* __restrict__ bias, const float* __restrict__ rowScale,
        int doRelu, int permD, int permStride) {
    __shared__ float As[8][128];
    __shared__ float Bs[8][128];
    const int tid = threadIdx.x;
    const int tx = tid & 15;
    const int ty = tid >> 4;
    const int bm = blockIdx.x * 128;
    const int bn = blockIdx.y * 128;

    const int arow = tid >> 1;
    const int akk = (tid & 1) * 4;
    const int brow = tid >> 5;
    const int bcol = (tid & 31) * 4;

    float acc[8][8];
#pragma unroll
    for (int i = 0; i < 8; ++i)
#pragma unroll
        for (int j = 0; j < 8; ++j) acc[i][j] = 0.0f;

    for (int k0 = 0; k0 < K; k0 += 8) {
        const int ar = bm + arow;
        float4 av;
        if (ar < M) av = *(const float4*)(A + (size_t)ar * K + k0 + akk);
        else av = make_float4(0.f, 0.f, 0.f, 0.f);
        As[akk + 0][arow] = av.x;
        As[akk + 1][arow] = av.y;
        As[akk + 2][arow] = av.z;
        As[akk + 3][arow] = av.w;
        const float4 bv = *(const float4*)(B + (size_t)(k0 + brow) * N + bn + bcol);
        *(float4*)&Bs[brow][bcol] = bv;
        __syncthreads();
#pragma unroll
        for (int k = 0; k < 8; ++k) {
            const float4 a0 = *(const float4*)&As[k][ty * 4];
            const float4 a1 = *(const float4*)&As[k][64 + ty * 4];
            const float4 b0 = *(const float4*)&Bs[k][tx * 4];
            const float4 b1 = *(const float4*)&Bs[k][64 + tx * 4];
            const float ar8[8] = {a0.x, a0.y, a0.z, a0.w, a1.x, a1.y, a1.z, a1.w};
            const float br8[8] = {b0.x, b0.y, b0.z, b0.w, b1.x, b1.y, b1.z, b1.w};
#pragma unroll
            for (int i = 0; i < 8; ++i)
#pragma unroll
                for (int j = 0; j < 8; ++j)
                    acc[i][j] = fmaf(ar8[i], br8[j], acc[i][j]);
        }
        __syncthreads();
    }

#pragma unroll
    for (int i = 0; i < 8; ++i) {
        const int r = bm + ((i < 4) ? (ty * 4 + i) : (64 + ty * 4 + (i - 4)));
        if (r >= M) continue;
        const float rs = rowScale ? rowScale[r] : 1.0f;
        size_t base;
        if (permD > 0) {
            const int rm = r % permD, rb = r / permD;
            base = (size_t)rm * permStride + (size_t)rb * N;
        } else {
            base = (size_t)r * (size_t)N;
        }
#pragma unroll
        for (int h = 0; h < 2; ++h) {
            const int c = bn + h * 64 + tx * 4;
            float4 v;
            v.x = acc[i][h * 4 + 0] * rs;
            v.y = acc[i][h * 4 + 1] * rs;
            v.z = acc[i][h * 4 + 2] * rs;
            v.w = acc[i][h * 4 + 3] * rs;
            if (bias) {
                v.x += bias[c + 0]; v.y += bias[c + 1];
                v.z += bias[c + 2]; v.w += bias[c + 3];
            }
            if (doRelu) {
                v.x = fmaxf(v.x, 0.f); v.y = fmaxf(v.y, 0.f);
                v.z = fmaxf(v.z, 0.f); v.w = fmaxf(v.w, 0.f);
            }
            *(float4*)(C + base + c) = v;
        }
    }
}

// ---------------------------------------------------------------- action projection ap[b,h]
__global__ __launch_bounds__(256) void k_actproj(const float* __restrict__ actions,
                                                 const float* __restrict__ Wq1,
                                                 float* __restrict__ ap) {
    const int b = blockIdx.x, h = threadIdx.x;
    float s = 0.0f;
#pragma unroll
    for (int a = 0; a < NA; ++a)
        s = fmaf(actions[b * NA + a], Wq1[(size_t)(NE + a) * NH + h], s);
    ap[b * NH + h] = s;
}

// ---------------------------------------------------------------- q pass: q[r] for all 64000 rows (r = n*32+b)
// q = relu(y0 + ap) . Wq2   (bq2 omitted: softmax-invariant)
__global__ __launch_bounds__(256) void k_qpass(const float* __restrict__ y0,
                                               const float* __restrict__ ap,
                                               const float* __restrict__ Wq2,
                                               float* __restrict__ q) {
    const int wave = threadIdx.x >> 6;
    const int lane = threadIdx.x & 63;
    const int r = blockIdx.x * 4 + wave;
    const int b = r & 31;
    const float4 y4 = *(const float4*)(y0 + (size_t)r * NH + lane * 4);
    const float4 a4 = *(const float4*)(ap + (size_t)b * NH + lane * 4);
    const float4 w4 = *(const float4*)(Wq2 + lane * 4);
    float s = fmaxf(y4.x + a4.x, 0.f) * w4.x + fmaxf(y4.y + a4.y, 0.f) * w4.y +
              fmaxf(y4.z + a4.z, 0.f) * w4.z + fmaxf(y4.w + a4.w, 0.f) * w4.w;
#pragma unroll
    for (int off = 32; off > 0; off >>= 1) s += __shfl_down(s, off);
    if (lane == 0) q[r] = s;
}

// ---------------------------------------------------------------- per-agent: softmax-argmax, action update, q2 at selected node
__global__ __launch_bounds__(256) void k_update(
        const float* __restrict__ q, const float* __restrict__ y0,
        const float* __restrict__ Wq1, const float* __restrict__ Wq2,
        const float* __restrict__ bq2, float* actions, float* out_q, int agent) {
    __shared__ float sh[256];
    __shared__ float act_sh[NA];
    __shared__ float sam_sh;
    const int b = blockIdx.x, t = threadIdx.x;
    if (t < NA) act_sh[t] = actions[b * NA + t];
    __syncthreads();
    // phase 1: max over n
    float m = -3.4e38f;
    for (int n = t; n < NN; n += 256) m = fmaxf(m, q[n * NB + b]);
    sh[t] = m; __syncthreads();
    for (int s = 128; s > 0; s >>= 1) {
        if (t < s) sh[t] = fmaxf(sh[t], sh[t + s]);
        __syncthreads();
    }
    const float qmax = sh[0]; __syncthreads();
    // phase 2: sum exp and sum exp*idx
    float s1 = 0.f, s2 = 0.f;
    for (int n = t; n < NN; n += 256) {
        float e = expf(q[n * NB + b] - qmax);
        s1 += e; s2 += e * (float)n;
    }
    sh[t] = s1; __syncthreads();
    for (int s = 128; s > 0; s >>= 1) { if (t < s) sh[t] += sh[t + s]; __syncthreads(); }
    s1 = sh[0]; __syncthreads();
    sh[t] = s2; __syncthreads();
    for (int s = 128; s > 0; s >>= 1) { if (t < s) sh[t] += sh[t + s]; __syncthreads(); }
    s2 = sh[0]; __syncthreads();
    float sam = s2 / s1;
    sam = fminf(fmaxf(sam, 0.0f), 2000.0f);
    if (t == 0) { actions[b * NA + agent] = sam / ACTION_NORM; sam_sh = sam; }
    __syncthreads();
    const float samv = sam_sh;
    const int nsel = (int)samv;
    // phase 3: q2 at node nsel with updated actions
    float apv = 0.0f;
#pragma unroll
    for (int a = 0; a < NA; ++a) {
        const float act = (a == agent) ? (samv / ACTION_NORM) : act_sh[a];
        apv = fmaf(act, Wq1[(size_t)(NE + a) * NH + t], apv);
    }
    const float v = fmaxf(y0[((size_t)nsel * NB + b) * NH + t] + apv, 0.0f) * Wq2[t];
    sh[t] = v; __syncthreads();
    for (int s = 128; s > 0; s >>= 1) { if (t < s) sh[t] += sh[t + s]; __syncthreads(); }
    if (t == 0) out_q[b * NA + agent] = sh[0] + bq2[0];
}

// ---------------------------------------------------------------- chosen actions (as float ints)
__global__ void k_chosen(const float* __restrict__ actions, float* __restrict__ out) {
    const int t = threadIdx.x;  // 256 = 32*8
    out[NB * NA + t] = (float)(int)(actions[t] * ACTION_NORM);
}

// ---------------------------------------------------------------- launch
extern "C" void kernel_launch(void* const* d_in, const int* in_sizes, int n_in,
                              void* d_out, int out_size, void* d_ws, size_t ws_size,
                              hipStream_t stream) {
    const float* state = (const float*)d_in[0];   // [32,2000,32]
    const float* dm    = (const float*)d_in[1];   // [2000,2000]
    const float* W1    = (const float*)d_in[2];   // [32,256]
    const float* b1    = (const float*)d_in[3];   // [256]
    const float* W2    = (const float*)d_in[4];   // [256,128]
    const float* b2    = (const float*)d_in[5];   // [128]
    const float* Wq1   = (const float*)d_in[6];   // [136,256]
    const float* bq1   = (const float*)d_in[7];   // [256]
    const float* Wq2   = (const float*)d_in[8];   // [256]
    const float* bq2   = (const float*)d_in[9];   // [1]
    const int* fa      = (const int*)d_in[10];    // [3,32]
    const int* fid     = (const int*)d_in[11];    // [3]
    float* out = (float*)d_out;                   // 256 q_values + 256 chosen
    float* ws = (float*)d_ws;

    // workspace layout (floats)
    float*    sim     = ws + 0;          // 4,000,000
    float*    inv_rs  = ws + 4000000;    // 2,048 (pad)
    unsigned* dmax_u  = (unsigned*)(ws + 4002048); // 64
    float*    actions = ws + 4002112;    // 512 (pad)
    float*    ap      = ws + 4002624;    // 8,192
    float*    qbuf    = ws + 4010816;    // 64,512 (pad)
    float*    ENC     = ws + 4075328;    // 8,192,000  [m][b][e] = [2000,4096]
    float*    X       = ws + 12267328;   // 8,192,000  [n][b][e] = rows (n*32+b) x 128
    float*    h1y0    = ws + 20459328;   // 16,384,000 h1 then y0 [64000,256]

    const int RTOT = NB * NN;  // 64000

    k_init<<<1, 256, 0, stream>>>(dmax_u, actions, fa, fid);
    k_max<<<1024, 256, 0, stream>>>(dm, dmax_u, NN * NN);
    k_sim<<<NN, 256, 0, stream>>>(dm, dmax_u, sim, inv_rs);

    // encoder layer 1: h1 = relu(state @ W1 + b1)   [64000,256]
    sgemm_k<<<dim3(RTOT / 128, NH / 128), 256, 0, stream>>>(
        state, W1, h1y0, RTOT, NH, NRD, b1, nullptr, 1, 0, 0);
    // encoder layer 2: ENC[m][b][e] = h1 @ W2 + b2  (permuted store)
    sgemm_k<<<dim3(RTOT / 128, NE / 128), 256, 0, stream>>>(
        h1y0, W2, ENC, RTOT, NE, NH, b2, nullptr, 0, NN, NB * NE);
    // graph conv: X = inv_rs * (sim @ ENC)   [2000,4096]
    sgemm_k<<<dim3((NN + 127) / 128, (NB * NE) / 128), 256, 0, stream>>>(
        sim, ENC, X, NN, NB * NE, NN, nullptr, inv_rs, 0, 0, 0);
    // y0 = X @ Wq1[:128] + bq1   [64000,256]  (rows = n*32+b)
    sgemm_k<<<dim3(RTOT / 128, NH / 128), 256, 0, stream>>>(
        X, Wq1, h1y0, RTOT, NH, NE, bq1, nullptr, 0, 0, 0);

    for (int ag = 0; ag < NA; ++ag) {
        k_actproj<<<NB, 256, 0, stream>>>(actions, Wq1, ap);
        k_qpass<<<RTOT / 4, 256, 0, stream>>>(h1y0, ap, Wq2, qbuf);
        k_update<<<NB, 256, 0, stream>>>(qbuf, h1y0, Wq1, Wq2, bq2, actions, out, ag);
    }
    k_chosen<<<1, NB * NA, 0, stream>>>(actions, out);
}

// Round 2
// 397.720 us; speedup vs baseline: 2.2143x; 2.2143x over previous
//
#include <hip/hip_runtime.h>
#include <cstddef>

#define NB 32
#define NN 2000
#define NRD 32
#define NE 128
#define NH 256
#define NA 8
#define KP 2016          // conv K padded to multiple of 32
#define ACTION_NORM 2000.0f

typedef unsigned short u16;
typedef __bf16 b16x8 __attribute__((ext_vector_type(8)));
typedef float f32x4 __attribute__((ext_vector_type(4)));
typedef const __attribute__((address_space(1))) unsigned int* gptr_t;
typedef __attribute__((address_space(3))) unsigned int* lptr_t;

__device__ inline u16 f2bf(float x) {
    unsigned u = __float_as_uint(x);
    u += 0x7FFFu + ((u >> 16) & 1u);
    return (u16)(u >> 16);
}
__device__ inline float bf2f(u16 h) { return __uint_as_float((unsigned)h << 16); }

// ---------------------------------------------------------------- init: dmax reset, actions, ap for agent 0
__global__ __launch_bounds__(256) void k_init(unsigned* dmax_u, float* actions, float* ap,
                                              const int* __restrict__ fa,
                                              const int* __restrict__ fid,
                                              const float* __restrict__ Wq1) {
    const int b = blockIdx.x, t = threadIdx.x;   // 32 blocks x 256
    __shared__ float act[NA];
    if (b == 0 && t == 0) *dmax_u = 0u;
    if (t < NA) {
        float v = -1.0f;
        for (int j = 0; j < 3; ++j)
            if (fid[j] == t) v = (float)fa[j * NB + b] / ACTION_NORM;
        act[t] = v;
        actions[b * NA + t] = v;
    }
    __syncthreads();
    float s = 0.0f;
#pragma unroll
    for (int a = 0; a < NA; ++a) s = fmaf(act[a], Wq1[(size_t)(NE + a) * NH + t], s);
    ap[b * NH + t] = s;
}

// ---------------------------------------------------------------- global max of dm
__global__ __launch_bounds__(256) void k_max(const float* __restrict__ dm,
                                             unsigned* dmax_u, int n) {
    __shared__ float sh[256];
    float m = 0.0f;
    for (int i = blockIdx.x * blockDim.x + threadIdx.x; i < n; i += gridDim.x * blockDim.x)
        m = fmaxf(m, dm[i]);
    sh[threadIdx.x] = m; __syncthreads();
    for (int s = 128; s > 0; s >>= 1) {
        if (threadIdx.x < s) sh[threadIdx.x] = fmaxf(sh[threadIdx.x], sh[threadIdx.x + s]);
        __syncthreads();
    }
    if (threadIdx.x == 0) atomicMax(dmax_u, __float_as_uint(sh[0]));
}

// ---------------------------------------------------------------- sim rows -> bf16 (K padded), inv rowsum
__global__ __launch_bounds__(256) void k_sim(const float* __restrict__ dm,
                                             const unsigned* __restrict__ dmax_u,
                                             u16* __restrict__ simb,
                                             float* __restrict__ inv_rs) {
    __shared__ float sh[256];
    const int n = blockIdx.x;
    const float inv = 1.0f / __uint_as_float(*dmax_u);
    float s = 0.0f;
    for (int m = threadIdx.x; m < KP; m += 256) {
        if (m < NN) {
            float e = expf(-dm[(size_t)n * NN + m] * inv);
            simb[(size_t)n * KP + m] = f2bf(e);
            s += e;
        } else {
            simb[(size_t)n * KP + m] = 0;
        }
    }
    sh[threadIdx.x] = s; __syncthreads();
    for (int st = 128; st > 0; st >>= 1) {
        if (threadIdx.x < st) sh[threadIdx.x] += sh[threadIdx.x + st];
        __syncthreads();
    }
    if (threadIdx.x == 0) inv_rs[n] = 1.0f / sh[0];
}

// ---------------------------------------------------------------- prep: convert state, transpose weights, zero ENC pad
#define PREP_STATE (64000 * 32)
#define PREP_W1T   (256 * 32)
#define PREP_W2T   (128 * 256)
#define PREP_WQ1T  (256 * 128)
#define PREP_PAD   (4096 * 16)
#define PREP_TOT   (PREP_STATE + PREP_W1T + PREP_W2T + PREP_WQ1T + PREP_PAD)
__global__ __launch_bounds__(256) void k_prep(const float* __restrict__ state,
                                              const float* __restrict__ W1,
                                              const float* __restrict__ W2,
                                              const float* __restrict__ Wq1,
                                              u16* __restrict__ state_b, u16* __restrict__ W1t,
                                              u16* __restrict__ W2t, u16* __restrict__ Wq1at,
                                              u16* __restrict__ ENCt) {
    int i = blockIdx.x * 256 + threadIdx.x;
    if (i < PREP_STATE) { state_b[i] = f2bf(state[i]); return; }
    i -= PREP_STATE;
    if (i < PREP_W1T) { int h = i >> 5, k = i & 31; W1t[i] = f2bf(W1[k * NH + h]); return; }
    i -= PREP_W1T;
    if (i < PREP_W2T) { int e = i >> 8, h = i & 255; W2t[i] = f2bf(W2[h * NE + e]); return; }
    i -= PREP_W2T;
    if (i < PREP_WQ1T) { int hq = i >> 7, e = i & 127; Wq1at[i] = f2bf(Wq1[e * NH + hq]); return; }
    i -= PREP_WQ1T;
    if (i < PREP_PAD) { int eb = i >> 4, mm = NN + (i & 15); ENCt[(size_t)eb * KP + mm] = 0; }
}

// ---------------------------------------------------------------- bf16 NT MFMA GEMM, 128x128 tile, BK=32
// C = A[M][K] * (Bt[N][K])^T ; out bf16. BMODE: 0 none, 1 bias[col], 2 bias[row].
// PERM (GEMM2 only): store at ((row*32 + col/2000)*KP + col%2000)
template<int RELU, int BMODE, int RSC, int PERM>
__global__ __launch_bounds__(256) void mfma_gemm(
        const u16* __restrict__ A, const u16* __restrict__ Bt, u16* __restrict__ C,
        int M, int N, int K, int lda, int ldb, int ldc,
        const float* __restrict__ bias, const float* __restrict__ rowScale) {
    __shared__ u16 lds[16 * 512];           // 16 chunks x 1KB (A: 0-7, B: 8-15)
    const int tid = threadIdx.x;
    const int w = tid >> 6, l = tid & 63;
    const int wr = w & 1, wc = w >> 1;
    const int bm = blockIdx.x * 128, bn = blockIdx.y * 128;
    const int lm = l & 15, lq = l >> 4;

    f32x4 acc[4][4] = {};

    for (int k0 = 0; k0 < K; k0 += 32) {
        __syncthreads();
#pragma unroll
        for (int i = 0; i < 4; ++i) {
            const int idx = w * 4 + i;
            const u16* gp;
            if (idx < 8) {
                int row = bm + idx * 16 + lm;
                row = row < M ? row : M - 1;
                gp = A + (size_t)row * lda + k0 + lq * 8;
            } else {
                const int col = bn + (idx - 8) * 16 + lm;
                gp = Bt + (size_t)col * ldb + k0 + lq * 8;
            }
            __builtin_amdgcn_global_load_lds((gptr_t)gp, (lptr_t)(lds + idx * 512), 16, 0, 0);
        }
        __syncthreads();
        b16x8 af[4], bf[4];
#pragma unroll
        for (int i = 0; i < 4; ++i) {
            af[i] = *(const b16x8*)(lds + (wr * 4 + i) * 512 + l * 8);
            bf[i] = *(const b16x8*)(lds + (8 + wc * 4 + i) * 512 + l * 8);
        }
#pragma unroll
        for (int fr = 0; fr < 4; ++fr)
#pragma unroll
            for (int fc = 0; fc < 4; ++fc)
                acc[fr][fc] = __builtin_amdgcn_mfma_f32_16x16x32_bf16(af[fr], bf[fc], acc[fr][fc], 0, 0, 0);
    }

#pragma unroll
    for (int fr = 0; fr < 4; ++fr) {
#pragma unroll
        for (int r = 0; r < 4; ++r) {
            const int row = bm + wr * 64 + fr * 16 + lq * 4 + r;
            if (row >= M) continue;
            const float rsv = RSC ? rowScale[row] : 1.0f;
#pragma unroll
            for (int fc = 0; fc < 4; ++fc) {
                const int col = bn + wc * 64 + fc * 16 + lm;
                float v = acc[fr][fc][r] * rsv;
                if (BMODE == 1) v += bias[col];
                if (BMODE == 2) v += bias[row];
                if (RELU) v = fmaxf(v, 0.0f);
                size_t addr;
                if (PERM) {
                    const unsigned bb = (unsigned)col / 2000u;
                    const unsigned mm = (unsigned)col - bb * 2000u;
                    addr = ((size_t)row * 32 + bb) * KP + mm;
                } else {
                    addr = (size_t)row * ldc + col;
                }
                C[addr] = f2bf(v);
            }
        }
    }
}

// ---------------------------------------------------------------- X[n][(e,b)] -> Xt[(n,b)][e]
__global__ __launch_bounds__(256) void k_xpose(const u16* __restrict__ X, u16* __restrict__ Xt) {
    __shared__ u16 tile[4096];
    const int n = blockIdx.x, t = threadIdx.x;
    const uint4* src = (const uint4*)(X + (size_t)n * 4096);
    ((uint4*)tile)[t] = src[t];
    ((uint4*)tile)[256 + t] = src[256 + t];
    __syncthreads();
    const int b = t >> 3, e0 = (t & 7) * 16;
    u16 tmp[16];
#pragma unroll
    for (int j = 0; j < 16; ++j) tmp[j] = tile[(e0 + j) * 32 + b];
    uint4* dst = (uint4*)(Xt + ((size_t)n * 32 + b) * 128 + e0);
    dst[0] = ((const uint4*)tmp)[0];
    dst[1] = ((const uint4*)tmp)[1];
}

// ---------------------------------------------------------------- q pass: one wave per row r=(n*32+b)
__global__ __launch_bounds__(256) void k_qpass(const u16* __restrict__ y0,
                                               const float* __restrict__ ap,
                                               const float* __restrict__ Wq2,
                                               float* __restrict__ q) {
    const int wave = threadIdx.x >> 6, lane = threadIdx.x & 63;
    const int r = blockIdx.x * 4 + wave;
    const int b = r & 31;
    const uint2 yv = *(const uint2*)(y0 + (size_t)r * NH + lane * 4);
    const float4 a4 = *(const float4*)(ap + b * NH + lane * 4);
    const float4 w4 = *(const float4*)(Wq2 + lane * 4);
    const float y0f = __uint_as_float(yv.x << 16);
    const float y1f = __uint_as_float(yv.x & 0xFFFF0000u);
    const float y2f = __uint_as_float(yv.y << 16);
    const float y3f = __uint_as_float(yv.y & 0xFFFF0000u);
    float s = fmaxf(y0f + a4.x, 0.f) * w4.x + fmaxf(y1f + a4.y, 0.f) * w4.y +
              fmaxf(y2f + a4.z, 0.f) * w4.z + fmaxf(y3f + a4.w, 0.f) * w4.w;
#pragma unroll
    for (int off = 32; off > 0; off >>= 1) s += __shfl_down(s, off);
    if (lane == 0) q[r] = s;
}

// ---------------------------------------------------------------- per-agent update (+ ap for next agent)
__global__ __launch_bounds__(256) void k_update(
        const float* __restrict__ q, const u16* __restrict__ y0,
        const float* __restrict__ Wq1, const float* __restrict__ Wq2,
        const float* __restrict__ bq2, float* actions, float* ap,
        float* out_q, int agent) {
    __shared__ float sh[256];
    __shared__ float act_sh[NA];
    __shared__ float sam_sh;
    const int b = blockIdx.x, t = threadIdx.x;
    if (t < NA) act_sh[t] = actions[b * NA + t];
    __syncthreads();
    float m = -3.4e38f;
    for (int n = t; n < NN; n += 256) m = fmaxf(m, q[n * NB + b]);
    sh[t] = m; __syncthreads();
    for (int s = 128; s > 0; s >>= 1) {
        if (t < s) sh[t] = fmaxf(sh[t], sh[t + s]);
        __syncthreads();
    }
    const float qmax = sh[0]; __syncthreads();
    float s1 = 0.f, s2 = 0.f;
    for (int n = t; n < NN; n += 256) {
        float e = expf(q[n * NB + b] - qmax);
        s1 += e; s2 += e * (float)n;
    }
    sh[t] = s1; __syncthreads();
    for (int s = 128; s > 0; s >>= 1) { if (t < s) sh[t] += sh[t + s]; __syncthreads(); }
    s1 = sh[0]; __syncthreads();
    sh[t] = s2; __syncthreads();
    for (int s = 128; s > 0; s >>= 1) { if (t < s) sh[t] += sh[t + s]; __syncthreads(); }
    s2 = sh[0]; __syncthreads();
    float sam = s2 / s1;
    sam = fminf(fmaxf(sam, 0.0f), 2000.0f);
    if (t == 0) { actions[b * NA + agent] = sam / ACTION_NORM; sam_sh = sam; }
    __syncthreads();
    const float samv = sam_sh;
    const int nsel = (int)samv;
    float apv = 0.0f;
#pragma unroll
    for (int a = 0; a < NA; ++a) {
        const float act = (a == agent) ? (samv / ACTION_NORM) : act_sh[a];
        apv = fmaf(act, Wq1[(size_t)(NE + a) * NH + t], apv);
    }
    ap[b * NH + t] = apv;   // ap for the next agent's qpass
    const float yv = bf2f(y0[((size_t)nsel * NB + b) * NH + t]);
    const float v = fmaxf(yv + apv, 0.0f) * Wq2[t];
    sh[t] = v; __syncthreads();
    for (int s = 128; s > 0; s >>= 1) { if (t < s) sh[t] += sh[t + s]; __syncthreads(); }
    if (t == 0) out_q[b * NA + agent] = sh[0] + bq2[0];
}

// ---------------------------------------------------------------- chosen actions
__global__ void k_chosen(const float* __restrict__ actions, float* __restrict__ out) {
    const int t = threadIdx.x;
    out[NB * NA + t] = (float)(int)(actions[t] * ACTION_NORM);
}

// ---------------------------------------------------------------- launch
extern "C" void kernel_launch(void* const* d_in, const int* in_sizes, int n_in,
                              void* d_out, int out_size, void* d_ws, size_t ws_size,
                              hipStream_t stream) {
    const float* state = (const float*)d_in[0];
    const float* dm    = (const float*)d_in[1];
    const float* W1    = (const float*)d_in[2];
    const float* b1    = (const float*)d_in[3];
    const float* W2    = (const float*)d_in[4];
    const float* b2    = (const float*)d_in[5];
    const float* Wq1   = (const float*)d_in[6];
    const float* bq1   = (const float*)d_in[7];
    const float* Wq2   = (const float*)d_in[8];
    const float* bq2   = (const float*)d_in[9];
    const int* fa      = (const int*)d_in[10];
    const int* fid     = (const int*)d_in[11];
    float* out = (float*)d_out;

    char* p = (char*)d_ws;
    u16* simb      = (u16*)p;      p += (size_t)NN * KP * 2;        // 8,064,000
    float* inv_rs  = (float*)p;    p += 2048 * 4;
    unsigned* dmax_u = (unsigned*)p; p += 256;
    float* actions = (float*)p;    p += 256 * 4;
    float* ap      = (float*)p;    p += 8192 * 4;
    float* qbuf    = (float*)p;    p += 64000 * 4;
    u16* state_b   = (u16*)p;      p += (size_t)2048000 * 2;
    u16* W1t       = (u16*)p;      p += 8192 * 2;
    u16* W2t       = (u16*)p;      p += 32768 * 2;
    u16* Wq1at     = (u16*)p;      p += 32768 * 2;
    u16* h1        = (u16*)p;      p += (size_t)16384000 * 2;
    u16* ENCt      = (u16*)p;      p += (size_t)4096 * KP * 2;      // 16,515,072
    u16* X         = (u16*)p;      p += (size_t)8192000 * 2;
    u16* Xt        = (u16*)p;      p += (size_t)8192000 * 2;
    u16* y0w       = (u16*)p;      p += (size_t)16384000 * 2;

    const int RTOT = NB * NN;  // 64000

    k_prep<<<(PREP_TOT + 255) / 256, 256, 0, stream>>>(state, W1, W2, Wq1,
                                                       state_b, W1t, W2t, Wq1at, ENCt);
    k_init<<<NB, 256, 0, stream>>>(dmax_u, actions, ap, fa, fid, Wq1);
    k_max<<<1024, 256, 0, stream>>>(dm, dmax_u, NN * NN);
    k_sim<<<NN, 256, 0, stream>>>(dm, dmax_u, simb, inv_rs);

    // enc1: h1 = relu(state @ W1 + b1)  [64000,256] bf16
    mfma_gemm<1, 1, 0, 0><<<dim3(RTOT / 128, NH / 128), 256, 0, stream>>>(
        state_b, W1t, h1, RTOT, NH, NRD, NRD, NRD, NH, b1, nullptr);
    // enc2 (transposed out): ENCt[(e,b)][m] = (W2t @ h1^T) + b2[row]  [128 x 64000] -> perm store
    mfma_gemm<0, 2, 0, 1><<<dim3(1, RTOT / 128), 256, 0, stream>>>(
        W2t, h1, ENCt, NE, RTOT, NH, NH, NH, 0, b2, nullptr);
    // conv: X[n][(e,b)] = inv_rs[n] * (simb @ ENCt^T)  [2000 x 4096]
    mfma_gemm<0, 0, 1, 0><<<dim3(16, 32), 256, 0, stream>>>(
        simb, ENCt, X, NN, 4096, KP, KP, KP, 4096, nullptr, inv_rs);
    k_xpose<<<NN, 256, 0, stream>>>(X, Xt);
    // y0 = Xt @ Wq1[:128] + bq1  [64000,256] bf16
    mfma_gemm<0, 1, 0, 0><<<dim3(RTOT / 128, NH / 128), 256, 0, stream>>>(
        Xt, Wq1at, y0w, RTOT, NH, NE, NE, NE, NH, bq1, nullptr);

    for (int ag = 0; ag < NA; ++ag) {
        k_qpass<<<RTOT / 4, 256, 0, stream>>>(y0w, ap, Wq2, qbuf);
        k_update<<<NB, 256, 0, stream>>>(qbuf, y0w, Wq1, Wq2, bq2, actions, ap, out, ag);
    }
    k_chosen<<<1, NB * NA, 0, stream>>>(actions, out);
}